// Round 9
// baseline (116.624 us; speedup 1.0000x reference)
//
#include <hip/hip_runtime.h>
#include <math.h>

#define LOG2PI_F 1.8378770664093453f
#define LOG2E_F  1.4426950408889634f
#define LN2_F    0.6931471805599453f
#define EXP_NEG1 0.36787944117144233f

#define ROWF   52      // floats per AC row: a[16] b[16] C[16] P pad[3]
#define CHROWS 512     // j-rows per LDS chunk (106.5 KB -> 1 block/CU, 16 waves)
#define ITI    8       // i-rows per block
#define NT     1024    // threads per block

__device__ __forceinline__ float exp2_(float x) { return __builtin_amdgcn_exp2f(x); }
__device__ __forceinline__ float log2_(float x) { return __builtin_amdgcn_logf(x); }

// ws layout (floats): wsPart[256] @0, counter(int) @256, AC[B*52] @1024

// ---------------- K1: coefficient precompute (+ counter zero) ---------------
// Quadratic form in v: e = a*v^2 + b*v (log2 domain), with a*m^2 folded into C.
__global__ __launch_bounds__(256) void k_prep(const float* __restrict__ mu,
                                              const float* __restrict__ lv,
                                              const int* __restrict__ nds,
                                              float* __restrict__ ws, int B) {
    if (blockIdx.x == 0 && threadIdx.x == 0) *(int*)(ws + 256) = 0;
    float* AC = ws + 1024;
    int idx = blockIdx.x * 256 + threadIdx.x;
    int j = idx >> 4, d = idx & 15;
    float m = mu[idx], l = lv[idx];
    float a = -0.5f * LOG2E_F * __expf(-l);
    float b = -2.0f * a * m;
    float ec = fmaf(-0.5f * LOG2E_F, l + LOG2PI_F, a * m * m);   // log2(C')

    float Nf = (float)(*nds);
    float Mf = (float)(B - 1);
    float strat = (Nf - Mf) / (Nf * Mf);
    float w = (j == 0) ? (1.0f / Nf) : ((j == 1) ? strat : (1.0f / Mf));

    float* row = AC + (size_t)j * ROWF;
    row[d] = a;
    row[16 + d] = b;
    row[32 + d] = w * exp2_(ec);
    float es = ec;
    es += __shfl_xor(es, 1); es += __shfl_xor(es, 2);
    es += __shfl_xor(es, 4); es += __shfl_xor(es, 8);
    if (d == 0) row[48] = w * exp2_(es);
}

// ---------------- K2: everything else, one launch ---------------------------
// grid 256 blocks x 1024 thr. Block owns 8 i's; lane owns 2 (il = t&3, +4q).
// jgrp = t>>2 (256 groups); chunk row = jgrp + 256k. 13 LDS reads serve 128 pairs.
__global__ __launch_bounds__(1024) void k_all(const float* __restrict__ ws_ac,
                                              const float* __restrict__ zg,
                                              const float* __restrict__ mu,
                                              const float* __restrict__ lv,
                                              const float4* __restrict__ x,
                                              const float4* __restrict__ r,
                                              const int* __restrict__ nds,
                                              float* __restrict__ wsPart,
                                              int* __restrict__ counter,
                                              float* __restrict__ out,
                                              int B, int n4,
                                              float invBF, float invB,
                                              int nblocks, int pb, int pil) {
    __shared__ float lds[CHROWS * ROWF];
    __shared__ float fin[16];
    __shared__ int lastFlag;

    const float* AC = ws_ac + 1024;
    const int t = threadIdx.x;
    const int bx = blockIdx.x;
    const int lane = t & 63, wv = t >> 6;
    const int il = t & 3;
    const int jgrp = t >> 2;

    // ---- recon slice ----
    float rec_s = 0.0f;
    {
        int per = (n4 + nblocks - 1) / nblocks;
        int lo = bx * per, hi = min(lo + per, n4);
        for (int u = lo + t; u < hi; u += NT) {
            float4 a = x[u], b = r[u];
            rec_s += fabsf(a.x - b.x) + fabsf(a.y - b.y) + fabsf(a.z - b.z) + fabsf(a.w - b.w);
        }
    }
    // ---- lqzx - lprior elements for this block's 8 i's ----
    float gab = 0.0f;
    if (t < ITI * 16) {
        int iw = t >> 4, d = t & 15;
        int idx = (bx * ITI + iw) * 16 + d;
        float m = mu[idx], l = lv[idx], zz = zg[idx];
        float tt = zz - m;
        float ga = -0.5f * (fmaf(tt * tt, __expf(-l), l) + LOG2PI_F);
        float gb = -0.5f * (fmaf(zz * zz, EXP_NEG1, 1.0f) + LOG2PI_F);
        gab = ga - gb;
    }
    // ---- z rows for my 2 i's ----
    float v[2][16];
    #pragma unroll
    for (int q = 0; q < 2; ++q) {
        const float4* zp = (const float4*)(zg + (size_t)(bx * ITI + il + 4 * q) * 16);
        float4 a0 = zp[0], a1 = zp[1], a2 = zp[2], a3 = zp[3];
        v[q][0]=a0.x; v[q][1]=a0.y; v[q][2]=a0.z; v[q][3]=a0.w;
        v[q][4]=a1.x; v[q][5]=a1.y; v[q][6]=a1.z; v[q][7]=a1.w;
        v[q][8]=a2.x; v[q][9]=a2.y; v[q][10]=a2.z; v[q][11]=a2.w;
        v[q][12]=a3.x; v[q][13]=a3.y; v[q][14]=a3.z; v[q][15]=a3.w;
    }

    float sd[2][16], stot[2];
    #pragma unroll
    for (int q = 0; q < 2; ++q) {
        stot[q] = 0.0f;
        #pragma unroll
        for (int d = 0; d < 16; ++d) sd[q][d] = 0.0f;
    }

    // ---- main loop: 4 chunks of 512 j-rows, 2 rows per lane per chunk ----
    const int nch = B / CHROWS;
    for (int c = 0; c < nch; ++c) {
        __syncthreads();
        {
            const float4* g = (const float4*)(AC + (size_t)c * CHROWS * ROWF);
            float4* s4 = (float4*)lds;
            for (int u = t; u < (CHROWS * ROWF) / 4; u += NT) s4[u] = g[u];
        }
        __syncthreads();
        #pragma unroll
        for (int k = 0; k < CHROWS / 256; ++k) {
            const float* rp = lds + (jgrp + 256 * k) * ROWF;
            float P = rp[48];
            float s2[2] = {0.0f, 0.0f};
            #pragma unroll
            for (int dq = 0; dq < 4; ++dq) {
                float4 aq = *(const float4*)(rp + dq * 4);
                float4 bq = *(const float4*)(rp + 16 + dq * 4);
                float4 cq = *(const float4*)(rp + 32 + dq * 4);
                const int d0 = dq * 4;
                #pragma unroll
                for (int q = 0; q < 2; ++q) {
                    float e0 = v[q][d0+0] * fmaf(aq.x, v[q][d0+0], bq.x);
                    float e1 = v[q][d0+1] * fmaf(aq.y, v[q][d0+1], bq.y);
                    float e2 = v[q][d0+2] * fmaf(aq.z, v[q][d0+2], bq.z);
                    float e3 = v[q][d0+3] * fmaf(aq.w, v[q][d0+3], bq.w);
                    s2[q] += (e0 + e1) + (e2 + e3);
                    sd[q][d0+0] = fmaf(cq.x, exp2_(e0), sd[q][d0+0]);
                    sd[q][d0+1] = fmaf(cq.y, exp2_(e1), sd[q][d0+1]);
                    sd[q][d0+2] = fmaf(cq.z, exp2_(e2), sd[q][d0+2]);
                    sd[q][d0+3] = fmaf(cq.w, exp2_(e3), sd[q][d0+3]);
                }
            }
            #pragma unroll
            for (int q = 0; q < 2; ++q) stot[q] = fmaf(P, exp2_(s2[q]), stot[q]);
        }
    }

    // ---- in-wave reduce over jgrp (lane bits 2..5) ----
    #pragma unroll
    for (int m = 4; m <= 32; m <<= 1) {
        #pragma unroll
        for (int q = 0; q < 2; ++q) {
            stot[q] += __shfl_xor(stot[q], m);
            #pragma unroll
            for (int d = 0; d < 16; ++d) sd[q][d] += __shfl_xor(sd[q][d], m);
        }
    }
    __syncthreads();                       // done reading lds; reuse for red
    if (lane < 4) {
        #pragma unroll
        for (int q = 0; q < 2; ++q) {
            float* wp = lds + (wv * 8 + lane + 4 * q) * 17;
            wp[0] = stot[q];
            #pragma unroll
            for (int d = 0; d < 16; ++d) wp[1 + d] = sd[q][d];
        }
    }
    __syncthreads();

    // ---- per-(il2,c) slot: cross-wave sum, patch, weighted log ----
    float contrib = 0.0f;
    if (t < ITI * 17) {                    // 136 threads
        int il2 = t / 17, cc = t % 17;     // i = bx*8 + il2
        float S = 0.0f;
        #pragma unroll
        for (int w = 0; w < 16; ++w) S += lds[w * 136 + t];

        if (bx == pb && il2 == pil) {
            const float* vv = zg + (size_t)(B - 2) * 16;
            float Nf = (float)(*nds);
            float Mf = (float)(B - 1);
            float dwN = (Nf - 2.0f * Mf) / Mf;      // (strat - 1/N) * N
            if (cc == 0) {
                float s2 = 0.0f;
                #pragma unroll
                for (int d = 0; d < 16; ++d)
                    s2 += vv[d] * fmaf(AC[d], vv[d], AC[16 + d]);
                S += dwN * AC[48] * exp2_(s2);
            } else {
                int d = cc - 1;
                float e = vv[d] * fmaf(AC[d], vv[d], AC[16 + d]);
                S += dwN * AC[32 + d] * exp2_(e);
            }
        }
        contrib = ((cc == 0) ? 3.0f : -3.0f) * log2_(S) * LN2_F;
    }

    // ---- block grand total ----
    float phi = rec_s * invBF + (gab + contrib) * invB;
    #pragma unroll
    for (int off = 32; off > 0; off >>= 1) phi += __shfl_down(phi, off);
    if (lane == 0) fin[wv] = phi;
    __syncthreads();
    if (t == 0) {
        float s = 0.0f;
        #pragma unroll
        for (int w = 0; w < 16; ++w) s += fin[w];
        __hip_atomic_store(&wsPart[bx], s, __ATOMIC_RELEASE, __HIP_MEMORY_SCOPE_AGENT);
        int old = __hip_atomic_fetch_add(counter, 1, __ATOMIC_ACQ_REL, __HIP_MEMORY_SCOPE_AGENT);
        lastFlag = (old == nblocks - 1);
    }
    __syncthreads();

    if (lastFlag) {
        float qv = 0.0f;
        if (t < nblocks)
            qv = __hip_atomic_load(&wsPart[t], __ATOMIC_ACQUIRE, __HIP_MEMORY_SCOPE_AGENT);
        #pragma unroll
        for (int off = 32; off > 0; off >>= 1) qv += __shfl_down(qv, off);
        __syncthreads();
        if (lane == 0) fin[wv] = qv;
        __syncthreads();
        if (t == 0) {
            float s = 0.0f;
            #pragma unroll
            for (int w = 0; w < 16; ++w) s += fin[w];
            out[0] = s;
        }
    }
}

extern "C" void kernel_launch(void* const* d_in, const int* in_sizes, int n_in,
                              void* d_out, int out_size, void* d_ws, size_t ws_size,
                              hipStream_t stream) {
    const float* x   = (const float*)d_in[0];
    const float* rec = (const float*)d_in[1];
    const float* mu  = (const float*)d_in[2];
    const float* lv  = (const float*)d_in[3];
    const float* z   = (const float*)d_in[4];
    const int*   nds = (const int*)d_in[5];

    const int BD = in_sizes[2];        // B * 16
    const int B  = BD / 16;            // 2048
    const int BF = in_sizes[0];        // B * F
    const int n4 = BF / 4;

    float* ws      = (float*)d_ws;
    float* wsPart  = ws;               // 256
    int*   counter = (int*)(ws + 256);
    const int nblocks = B / ITI;       // 256
    const int pb  = (B - 2) / ITI;
    const int pil = (B - 2) % ITI;

    k_prep<<<BD / 256, 256, 0, stream>>>(mu, lv, nds, ws, B);
    k_all<<<nblocks, NT, 0, stream>>>(ws, z, mu, lv,
                                      (const float4*)x, (const float4*)rec, nds,
                                      wsPart, counter, (float*)d_out,
                                      B, n4, 1.0f / (float)BF, 1.0f / (float)B,
                                      nblocks, pb, pil);
}